// Round 2
// baseline (1003.185 us; speedup 1.0000x reference)
//
#include <hip/hip_runtime.h>
#include <hip/hip_bf16.h>
#include <stdint.h>

// Problem constants
#define T_TREES 16
#define B_ROWS  8192
#define DIN     512
#define DH      1024
#define DOUT    256

typedef unsigned short u16;
typedef __attribute__((ext_vector_type(8))) short short8;
typedef __attribute__((ext_vector_type(4))) float floatx4;

// round-to-nearest-even fp32 -> bf16
__device__ __forceinline__ u16 f2bf(float f) {
    union { float f; uint32_t u; } v; v.f = f;
    uint32_t u = v.u;
    uint32_t r = (u + 0x7fffu + ((u >> 16) & 1u)) >> 16;
    return (u16)r;
}

// async 16B/lane global->LDS (lands at wave-uniform base + lane*16)
__device__ __forceinline__ void async_copy16(const u16* g, u16* l) {
    __builtin_amdgcn_global_load_lds(
        (const __attribute__((address_space(1))) uint32_t*)g,
        (__attribute__((address_space(3))) uint32_t*)l,
        16, 0, 0);
}

// ---------------------------------------------------------------------------
// Convert x (fp32 [M][K]) to bf16, contiguous. 4 elems/thread via float4.
__global__ void convert_x_kernel(const float* __restrict__ in, u16* __restrict__ out, int n4) {
    int idx = blockIdx.x * 256 + threadIdx.x;
    if (idx < n4) {
        float4 v = ((const float4*)in)[idx];
        ushort4 o;
        o.x = f2bf(v.x); o.y = f2bf(v.y); o.z = f2bf(v.z); o.w = f2bf(v.w);
        ((ushort4*)out)[idx] = o;
    }
}

// Convert + transpose weights: in fp32 [G][K][N] -> out bf16 [G][N][K], *scale.
// 32x32 tile through LDS; grid (K/32, N/32, G), 256 threads.
__global__ void convert_transpose_kernel(const float* __restrict__ in, u16* __restrict__ out,
                                         int K, int N, float scale) {
    __shared__ float tile[32][33];
    int t = blockIdx.z;
    int k0 = blockIdx.x * 32, n0 = blockIdx.y * 32;
    const float* inb = in + (size_t)t * K * N;
    u16* outb = out + (size_t)t * K * N;
    int c = threadIdx.x & 31, rg = threadIdx.x >> 5;  // col 0..31, rowgroup 0..7
#pragma unroll
    for (int i = 0; i < 4; i++) {
        int r = rg * 4 + i;
        tile[r][c] = inb[(size_t)(k0 + r) * N + n0 + c];
    }
    __syncthreads();
#pragma unroll
    for (int i = 0; i < 4; i++) {
        int r = rg * 4 + i;  // n within tile
        outb[(size_t)(n0 + r) * K + k0 + c] = f2bf(tile[c][r] * scale);
    }
}

// out[b][o] = mean_t b3[t][o]  (pre-writes bias so gemm_final can atomicAdd)
__global__ void init_out_kernel(const float* __restrict__ b3, float* __restrict__ out) {
    int idx = blockIdx.x * 256 + threadIdx.x;  // 8192*256 total
    int o = idx & (DOUT - 1);
    float s = 0.f;
#pragma unroll
    for (int t = 0; t < T_TREES; t++) s += b3[t * DOUT + o];
    out[idx] = s * (1.f / T_TREES);
}

// ---------------------------------------------------------------------------
// Batched GEMM + bias + ReLU, bf16 out.  C[t] = relu(A[t] @ B[t]^T + bias[t])
// A: bf16 [M][K] (per-t stride aStrideT elems; 0 = shared x)
// Bt: bf16 [G][N][K] (transposed weights), bias fp32 [G][N], C bf16 [G][M][N]
// 128x128 block tile, 4 waves as 2x2 of 64x64, 4x4 frags of 16x16x32 MFMA.
__global__ __launch_bounds__(256, 2)
void gemm_relu_bf16(const u16* __restrict__ A, size_t aStrideT,
                    const u16* __restrict__ Bt,
                    const float* __restrict__ bias,
                    u16* __restrict__ C,
                    int M, int N, int K) {
    __shared__ u16 ldsA[128 * 32];
    __shared__ u16 ldsB[128 * 32];

    const int t = blockIdx.z;
    const u16* Ab = A + (size_t)t * aStrideT;
    const u16* Bb = Bt + (size_t)t * (size_t)N * K;
    u16* Cb = C + (size_t)t * (size_t)M * N;
    const float* biasb = bias + (size_t)t * N;

    const int m0 = blockIdx.x * 128;
    const int n0 = blockIdx.y * 128;

    const int tid = threadIdx.x;
    const int wave = tid >> 6;
    const int lane = tid & 63;
    const int quad = lane >> 4;
    const int l16 = lane & 15;
    const int wm = (wave >> 1) * 64;
    const int wn = (wave & 1) * 64;

    // staging: 8 instrs/tile, 2 per wave; instr j covers rows j*16..j*16+15
    const int j0 = wave * 2, j1 = wave * 2 + 1;
    const int sRow0 = j0 * 16 + (lane >> 2);
    const int sRow1 = j1 * 16 + (lane >> 2);
    const int sCol = (lane & 3) * 8;  // element offset in 32-wide K slab

    floatx4 acc[4][4];
    const floatx4 zero = {0.f, 0.f, 0.f, 0.f};
#pragma unroll
    for (int i = 0; i < 4; i++)
#pragma unroll
        for (int j = 0; j < 4; j++) acc[i][j] = zero;

    for (int kk = 0; kk < K; kk += 32) {
        async_copy16(Ab + (size_t)(m0 + sRow0) * K + kk + sCol, &ldsA[j0 * 512]);
        async_copy16(Ab + (size_t)(m0 + sRow1) * K + kk + sCol, &ldsA[j1 * 512]);
        async_copy16(Bb + (size_t)(n0 + sRow0) * K + kk + sCol, &ldsB[j0 * 512]);
        async_copy16(Bb + (size_t)(n0 + sRow1) * K + kk + sCol, &ldsB[j1 * 512]);
        __syncthreads();

        short8 a[4], b[4];
#pragma unroll
        for (int mi = 0; mi < 4; mi++)
            a[mi] = *(const short8*)&ldsA[(wm + mi * 16 + l16) * 32 + quad * 8];
#pragma unroll
        for (int ni = 0; ni < 4; ni++)
            b[ni] = *(const short8*)&ldsB[(wn + ni * 16 + l16) * 32 + quad * 8];
#pragma unroll
        for (int mi = 0; mi < 4; mi++)
#pragma unroll
            for (int ni = 0; ni < 4; ni++)
                acc[mi][ni] = __builtin_amdgcn_mfma_f32_16x16x32_bf16(a[mi], b[ni], acc[mi][ni], 0, 0, 0);
        __syncthreads();
    }

    // epilogue: C/D layout col = lane&15, row = quad*4 + reg
#pragma unroll
    for (int ni = 0; ni < 4; ni++) {
        const int n = n0 + wn + ni * 16 + l16;
        const float bv = biasb[n];
#pragma unroll
        for (int mi = 0; mi < 4; mi++) {
#pragma unroll
            for (int i = 0; i < 4; i++) {
                const int m = m0 + wm + mi * 16 + quad * 4 + i;
                float v = acc[mi][ni][i] + bv;
                v = v > 0.f ? v : 0.f;
                Cb[(size_t)m * N + n] = f2bf(v);
            }
        }
    }
}

// ---------------------------------------------------------------------------
// Final layer + mean over trees as split-K GEMM with fp32 atomicAdd epilogue.
// H2 bf16 [G][M][DH]; W3t bf16 [G][DOUT][DH] (pre-scaled by 1/16);
// Out fp32 [M][DOUT], pre-initialized with mean bias. tpb trees per z-block.
__global__ __launch_bounds__(256, 2)
void gemm_final(const u16* __restrict__ H2, const u16* __restrict__ W3t,
                float* __restrict__ Out, int tpb) {
    constexpr int M = B_ROWS, N = DOUT, K = DH;
    __shared__ u16 ldsA[128 * 32];
    __shared__ u16 ldsB[128 * 32];

    const int m0 = blockIdx.x * 128;
    const int n0 = blockIdx.y * 128;

    const int tid = threadIdx.x;
    const int wave = tid >> 6;
    const int lane = tid & 63;
    const int quad = lane >> 4;
    const int l16 = lane & 15;
    const int wm = (wave >> 1) * 64;
    const int wn = (wave & 1) * 64;

    const int j0 = wave * 2, j1 = wave * 2 + 1;
    const int sRow0 = j0 * 16 + (lane >> 2);
    const int sRow1 = j1 * 16 + (lane >> 2);
    const int sCol = (lane & 3) * 8;

    floatx4 acc[4][4];
    const floatx4 zero = {0.f, 0.f, 0.f, 0.f};
#pragma unroll
    for (int i = 0; i < 4; i++)
#pragma unroll
        for (int j = 0; j < 4; j++) acc[i][j] = zero;

    for (int tt = 0; tt < tpb; tt++) {
        const int t = blockIdx.z * tpb + tt;
        const u16* Ab = H2 + (size_t)t * M * K;
        const u16* Bb = W3t + (size_t)t * N * K;
        for (int kk = 0; kk < K; kk += 32) {
            async_copy16(Ab + (size_t)(m0 + sRow0) * K + kk + sCol, &ldsA[j0 * 512]);
            async_copy16(Ab + (size_t)(m0 + sRow1) * K + kk + sCol, &ldsA[j1 * 512]);
            async_copy16(Bb + (size_t)(n0 + sRow0) * K + kk + sCol, &ldsB[j0 * 512]);
            async_copy16(Bb + (size_t)(n0 + sRow1) * K + kk + sCol, &ldsB[j1 * 512]);
            __syncthreads();

            short8 a[4], b[4];
#pragma unroll
            for (int mi = 0; mi < 4; mi++)
                a[mi] = *(const short8*)&ldsA[(wm + mi * 16 + l16) * 32 + quad * 8];
#pragma unroll
            for (int ni = 0; ni < 4; ni++)
                b[ni] = *(const short8*)&ldsB[(wn + ni * 16 + l16) * 32 + quad * 8];
#pragma unroll
            for (int mi = 0; mi < 4; mi++)
#pragma unroll
                for (int ni = 0; ni < 4; ni++)
                    acc[mi][ni] = __builtin_amdgcn_mfma_f32_16x16x32_bf16(a[mi], b[ni], acc[mi][ni], 0, 0, 0);
            __syncthreads();
        }
    }

#pragma unroll
    for (int ni = 0; ni < 4; ni++) {
        const int n = n0 + wn + ni * 16 + l16;
#pragma unroll
        for (int mi = 0; mi < 4; mi++) {
#pragma unroll
            for (int i = 0; i < 4; i++) {
                const int m = m0 + wm + mi * 16 + quad * 4 + i;
                atomicAdd(&Out[(size_t)m * N + n], acc[mi][ni][i]);
            }
        }
    }
}

// ---------------------------------------------------------------------------
extern "C" void kernel_launch(void* const* d_in, const int* in_sizes, int n_in,
                              void* d_out, int out_size, void* d_ws, size_t ws_size,
                              hipStream_t stream) {
    const float* x  = (const float*)d_in[0];
    const float* W1 = (const float*)d_in[1];
    const float* b1 = (const float*)d_in[2];
    const float* W2 = (const float*)d_in[3];
    const float* b2 = (const float*)d_in[4];
    const float* W3 = (const float*)d_in[5];
    const float* b3 = (const float*)d_in[6];
    float* out = (float*)d_out;

    // --- adaptive workspace layout -----------------------------------------
    // fixed: xb bf16 [8192][512] = 8 MB
    // per tree in a group: W1t 1 MB + W2t 2 MB + W3t 0.5 MB + h1 16 MB + h2 16 MB
    //                    = 37,224,448 B
    const size_t XB_BYTES  = 8388608ull;
    const size_t PER_TREE  = 37224448ull;
    int g = 16;
    while (g > 1 && XB_BYTES + (size_t)g * PER_TREE > ws_size) g >>= 1;
    const int nG = T_TREES / g;

    uint8_t* ws = (uint8_t*)d_ws;
    u16* xb  = (u16*)ws;
    uint8_t* gr = ws + XB_BYTES;
    u16* W1b = (u16*)gr;                                   // g * 1,048,576 B
    u16* W2b = (u16*)(gr + (size_t)g * 1048576ull);        // g * 2,097,152 B
    u16* W3b = (u16*)(gr + (size_t)g * 3145728ull);        // g *   524,288 B
    u16* h1  = (u16*)(gr + (size_t)g * 3670016ull);        // g * 16,777,216 B
    u16* h2  = (u16*)(gr + (size_t)g * 20447232ull);       // g * 16,777,216 B

    convert_x_kernel<<<4096, 256, 0, stream>>>(x, xb, (B_ROWS * DIN) / 4);
    init_out_kernel<<<(B_ROWS * DOUT) / 256, 256, 0, stream>>>(b3, out);

    for (int gi = 0; gi < nG; gi++) {
        const int t0 = gi * g;
        convert_transpose_kernel<<<dim3(DIN / 32, DH / 32, g), 256, 0, stream>>>(
            W1 + (size_t)t0 * DIN * DH, W1b, DIN, DH, 1.f);
        convert_transpose_kernel<<<dim3(DH / 32, DH / 32, g), 256, 0, stream>>>(
            W2 + (size_t)t0 * DH * DH, W2b, DH, DH, 1.f);
        convert_transpose_kernel<<<dim3(DH / 32, DOUT / 32, g), 256, 0, stream>>>(
            W3 + (size_t)t0 * DH * DOUT, W3b, DH, DOUT, 1.f / T_TREES);

        gemm_relu_bf16<<<dim3(B_ROWS / 128, DH / 128, g), 256, 0, stream>>>(
            xb, 0, W1b, b1 + (size_t)t0 * DH, h1, B_ROWS, DH, DIN);
        gemm_relu_bf16<<<dim3(B_ROWS / 128, DH / 128, g), 256, 0, stream>>>(
            h1, (size_t)B_ROWS * DH, W2b, b2 + (size_t)t0 * DH, h2, B_ROWS, DH, DH);

        const int tpb = g < 4 ? g : 4;
        gemm_final<<<dim3(B_ROWS / 128, DOUT / 128, g / tpb), 256, 0, stream>>>(
            h2, W3b, out, tpb);
    }
}

// Round 3
// 867.963 us; speedup vs baseline: 1.1558x; 1.1558x over previous
//
#include <hip/hip_runtime.h>
#include <hip/hip_bf16.h>
#include <stdint.h>

// Problem constants
#define T_TREES 16
#define B_ROWS  8192
#define DIN     512
#define DH      1024
#define DOUT    256

typedef unsigned short u16;
typedef __attribute__((ext_vector_type(8))) short short8;
typedef __attribute__((ext_vector_type(4))) float floatx4;

// round-to-nearest-even fp32 -> bf16
__device__ __forceinline__ u16 f2bf(float f) {
    union { float f; uint32_t u; } v; v.f = f;
    uint32_t u = v.u;
    uint32_t r = (u + 0x7fffu + ((u >> 16) & 1u)) >> 16;
    return (u16)r;
}

// async 16B/lane global->LDS (lands at wave-uniform base + lane*16)
__device__ __forceinline__ void async_copy16(const u16* g, u16* l) {
    __builtin_amdgcn_global_load_lds(
        (const __attribute__((address_space(1))) uint32_t*)g,
        (__attribute__((address_space(3))) uint32_t*)l,
        16, 0, 0);
}

// ---------------------------------------------------------------------------
__global__ void convert_x_kernel(const float* __restrict__ in, u16* __restrict__ out, int n4) {
    int idx = blockIdx.x * 256 + threadIdx.x;
    if (idx < n4) {
        float4 v = ((const float4*)in)[idx];
        ushort4 o;
        o.x = f2bf(v.x); o.y = f2bf(v.y); o.z = f2bf(v.z); o.w = f2bf(v.w);
        ((ushort4*)out)[idx] = o;
    }
}

// Convert + transpose weights: in fp32 [G][K][N] -> out bf16 [G][N][K], *scale.
__global__ void convert_transpose_kernel(const float* __restrict__ in, u16* __restrict__ out,
                                         int K, int N, float scale) {
    __shared__ float tile[32][33];
    int t = blockIdx.z;
    int k0 = blockIdx.x * 32, n0 = blockIdx.y * 32;
    const float* inb = in + (size_t)t * K * N;
    u16* outb = out + (size_t)t * K * N;
    int c = threadIdx.x & 31, rg = threadIdx.x >> 5;
#pragma unroll
    for (int i = 0; i < 4; i++) {
        int r = rg * 4 + i;
        tile[r][c] = inb[(size_t)(k0 + r) * N + n0 + c];
    }
    __syncthreads();
#pragma unroll
    for (int i = 0; i < 4; i++) {
        int r = rg * 4 + i;
        outb[(size_t)(n0 + r) * K + k0 + c] = f2bf(tile[c][r] * scale);
    }
}

// out[b][o] = mean_t b3[t][o]  (pre-writes bias so gemm_final can atomicAdd)
__global__ void init_out_kernel(const float* __restrict__ b3, float* __restrict__ out) {
    int idx = blockIdx.x * 256 + threadIdx.x;
    int o = idx & (DOUT - 1);
    float s = 0.f;
#pragma unroll
    for (int t = 0; t < T_TREES; t++) s += b3[t * DOUT + o];
    out[idx] = s * (1.f / T_TREES);
}

// ---------------------------------------------------------------------------
// Batched GEMM + bias + ReLU, bf16 out.  C[t] = relu(A[t] @ B[t]^T + bias[t])
// BK=64 K-slab (32 KB LDS), halves barrier count vs BK=32.
// LDS layout swizzle: the two 32-elem k-halves of each row are XOR-swapped by
// row parity so fragment ds_read_b128 spreads over all 32 banks (naive BK=64
// puts every row at bank 0 -> 16-way conflict). Verified: read-back of LDS
// col (h^parity)*32+q*8+u yields global col h*32+q*8+u; 8 dwords/bank (min).
__global__ __launch_bounds__(256, 2)
void gemm_relu_bf16(const u16* __restrict__ A, size_t aStrideT,
                    const u16* __restrict__ Bt,
                    const float* __restrict__ bias,
                    u16* __restrict__ C,
                    int M, int N, int K) {
    __shared__ u16 ldsA[128 * 64];
    __shared__ u16 ldsB[128 * 64];

    const int t = blockIdx.z;
    const u16* Ab = A + (size_t)t * aStrideT;
    const u16* Bb = Bt + (size_t)t * (size_t)N * K;
    u16* Cb = C + (size_t)t * (size_t)M * N;
    const float* biasb = bias + (size_t)t * N;

    const int m0 = blockIdx.x * 128;
    const int n0 = blockIdx.y * 128;

    const int tid = threadIdx.x;
    const int wave = tid >> 6;
    const int lane = tid & 63;
    const int quad = lane >> 4;
    const int l16 = lane & 15;
    const int wm = (wave >> 1) * 64;
    const int wn = (wave & 1) * 64;

    // staging: 16 instrs per matrix per slab, 4 per wave; instr j covers
    // LDS rows j*8 .. j*8+7 (each row = 64 elems = 128 B).
    const int s = lane >> 3;        // sub-row 0..7 within instr
    const int c8 = lane & 7;        // 16B chunk within row
    const int p = s & 1;            // row parity (j*8 is even)
    const int colElem = ((c8 ^ (p << 2)) << 3);  // swizzled col 0..63

    // fragment read: row parity for this lane's A/B rows
    const int ph = l16 & 1;

    floatx4 acc[4][4];
    const floatx4 zero = {0.f, 0.f, 0.f, 0.f};
#pragma unroll
    for (int i = 0; i < 4; i++)
#pragma unroll
        for (int j = 0; j < 4; j++) acc[i][j] = zero;

    for (int kk = 0; kk < K; kk += 64) {
#pragma unroll
        for (int i = 0; i < 4; i++) {
            const int j = wave * 4 + i;
            const int r = j * 8 + s;
            async_copy16(Ab + (size_t)(m0 + r) * K + kk + colElem, &ldsA[j * 512]);
            async_copy16(Bb + (size_t)(n0 + r) * K + kk + colElem, &ldsB[j * 512]);
        }
        __syncthreads();

#pragma unroll
        for (int h = 0; h < 2; h++) {
            const int ch = (h ^ ph) << 5;  // swizzled k-half select
            short8 a[4], b[4];
#pragma unroll
            for (int mi = 0; mi < 4; mi++)
                a[mi] = *(const short8*)&ldsA[(wm + mi * 16 + l16) * 64 + ch + quad * 8];
#pragma unroll
            for (int ni = 0; ni < 4; ni++)
                b[ni] = *(const short8*)&ldsB[(wn + ni * 16 + l16) * 64 + ch + quad * 8];
#pragma unroll
            for (int mi = 0; mi < 4; mi++)
#pragma unroll
                for (int ni = 0; ni < 4; ni++)
                    acc[mi][ni] = __builtin_amdgcn_mfma_f32_16x16x32_bf16(a[mi], b[ni], acc[mi][ni], 0, 0, 0);
        }
        __syncthreads();
    }

    // epilogue: C/D layout col = lane&15, row = quad*4 + reg
#pragma unroll
    for (int ni = 0; ni < 4; ni++) {
        const int n = n0 + wn + ni * 16 + l16;
        const float bv = biasb[n];
#pragma unroll
        for (int mi = 0; mi < 4; mi++) {
#pragma unroll
            for (int i = 0; i < 4; i++) {
                const int m = m0 + wm + mi * 16 + quad * 4 + i;
                float v = acc[mi][ni][i] + bv;
                v = v > 0.f ? v : 0.f;
                Cb[(size_t)m * N + n] = f2bf(v);
            }
        }
    }
}

// ---------------------------------------------------------------------------
// Final layer + mean: one tree per z-block, split across trees for occupancy.
// H2 bf16 [g][M][DH]; W3t bf16 [g][DOUT][DH] (pre-scaled by 1/16);
// Out fp32 [M][DOUT], pre-initialized with mean bias; fp32 atomicAdd.
__global__ __launch_bounds__(256, 2)
void gemm_final(const u16* __restrict__ H2, const u16* __restrict__ W3t,
                float* __restrict__ Out) {
    constexpr int M = B_ROWS, N = DOUT, K = DH;
    __shared__ u16 ldsA[128 * 32];
    __shared__ u16 ldsB[128 * 32];

    const int m0 = blockIdx.x * 128;
    const int n0 = blockIdx.y * 128;
    const int t = blockIdx.z;

    const int tid = threadIdx.x;
    const int wave = tid >> 6;
    const int lane = tid & 63;
    const int quad = lane >> 4;
    const int l16 = lane & 15;
    const int wm = (wave >> 1) * 64;
    const int wn = (wave & 1) * 64;

    const int j0 = wave * 2, j1 = wave * 2 + 1;
    const int sRow0 = j0 * 16 + (lane >> 2);
    const int sRow1 = j1 * 16 + (lane >> 2);
    const int sCol = (lane & 3) * 8;

    floatx4 acc[4][4];
    const floatx4 zero = {0.f, 0.f, 0.f, 0.f};
#pragma unroll
    for (int i = 0; i < 4; i++)
#pragma unroll
        for (int j = 0; j < 4; j++) acc[i][j] = zero;

    const u16* Ab = H2 + (size_t)t * M * K;
    const u16* Bb = W3t + (size_t)t * N * K;
    for (int kk = 0; kk < K; kk += 32) {
        async_copy16(Ab + (size_t)(m0 + sRow0) * K + kk + sCol, &ldsA[j0 * 512]);
        async_copy16(Ab + (size_t)(m0 + sRow1) * K + kk + sCol, &ldsA[j1 * 512]);
        async_copy16(Bb + (size_t)(n0 + sRow0) * K + kk + sCol, &ldsB[j0 * 512]);
        async_copy16(Bb + (size_t)(n0 + sRow1) * K + kk + sCol, &ldsB[j1 * 512]);
        __syncthreads();

        short8 a[4], b[4];
#pragma unroll
        for (int mi = 0; mi < 4; mi++)
            a[mi] = *(const short8*)&ldsA[(wm + mi * 16 + l16) * 32 + quad * 8];
#pragma unroll
        for (int ni = 0; ni < 4; ni++)
            b[ni] = *(const short8*)&ldsB[(wn + ni * 16 + l16) * 32 + quad * 8];
#pragma unroll
        for (int mi = 0; mi < 4; mi++)
#pragma unroll
            for (int ni = 0; ni < 4; ni++)
                acc[mi][ni] = __builtin_amdgcn_mfma_f32_16x16x32_bf16(a[mi], b[ni], acc[mi][ni], 0, 0, 0);
        __syncthreads();
    }

#pragma unroll
    for (int ni = 0; ni < 4; ni++) {
        const int n = n0 + wn + ni * 16 + l16;
#pragma unroll
        for (int mi = 0; mi < 4; mi++) {
#pragma unroll
            for (int i = 0; i < 4; i++) {
                const int m = m0 + wm + mi * 16 + quad * 4 + i;
                atomicAdd(&Out[(size_t)m * N + n], acc[mi][ni][i]);
            }
        }
    }
}

// ---------------------------------------------------------------------------
extern "C" void kernel_launch(void* const* d_in, const int* in_sizes, int n_in,
                              void* d_out, int out_size, void* d_ws, size_t ws_size,
                              hipStream_t stream) {
    const float* x  = (const float*)d_in[0];
    const float* W1 = (const float*)d_in[1];
    const float* b1 = (const float*)d_in[2];
    const float* W2 = (const float*)d_in[3];
    const float* b2 = (const float*)d_in[4];
    const float* W3 = (const float*)d_in[5];
    const float* b3 = (const float*)d_in[6];
    float* out = (float*)d_out;

    // --- workspace layout ---------------------------------------------------
    // fixed: xb 8 MB + all-tree weights (W1b 16 MB, W2b 32 MB, W3b 8 MB) = 64 MB
    // per tree in a group: h1 16 MB + h2 16 MB = 33,554,432 B
    const size_t XB_BYTES = 8388608ull;
    const size_t W1B_BYTES = 16777216ull, W2B_BYTES = 33554432ull, W3B_BYTES = 8388608ull;
    const size_t FIXED = XB_BYTES + W1B_BYTES + W2B_BYTES + W3B_BYTES;  // 67,108,864
    const size_t PER_TREE = 33554432ull;

    uint8_t* ws = (uint8_t*)d_ws;
    u16* xb  = (u16*)ws;
    u16* W1b = (u16*)(ws + XB_BYTES);
    u16* W2b = (u16*)(ws + XB_BYTES + W1B_BYTES);
    u16* W3b = (u16*)(ws + XB_BYTES + W1B_BYTES + W2B_BYTES);
    u16* h1  = (u16*)(ws + FIXED);

    int g = 16;
    while (g > 1 && FIXED + (size_t)g * PER_TREE > ws_size) g >>= 1;
    const int nG = T_TREES / g;
    u16* h2 = (u16*)(ws + FIXED + (size_t)g * (PER_TREE / 2));

    convert_x_kernel<<<4096, 256, 0, stream>>>(x, xb, (B_ROWS * DIN) / 4);
    init_out_kernel<<<(B_ROWS * DOUT) / 256, 256, 0, stream>>>(b3, out);
    convert_transpose_kernel<<<dim3(DIN / 32, DH / 32, T_TREES), 256, 0, stream>>>(W1, W1b, DIN, DH, 1.f);
    convert_transpose_kernel<<<dim3(DH / 32, DH / 32, T_TREES), 256, 0, stream>>>(W2, W2b, DH, DH, 1.f);
    convert_transpose_kernel<<<dim3(DH / 32, DOUT / 32, T_TREES), 256, 0, stream>>>(W3, W3b, DH, DOUT, 1.f / T_TREES);

    for (int gi = 0; gi < nG; gi++) {
        const int t0 = gi * g;
        gemm_relu_bf16<<<dim3(B_ROWS / 128, DH / 128, g), 256, 0, stream>>>(
            xb, 0, W1b + (size_t)t0 * DIN * DH, b1 + (size_t)t0 * DH, h1, B_ROWS, DH, DIN);
        gemm_relu_bf16<<<dim3(B_ROWS / 128, DH / 128, g), 256, 0, stream>>>(
            h1, (size_t)B_ROWS * DH, W2b + (size_t)t0 * DH * DH, b2 + (size_t)t0 * DH, h2, B_ROWS, DH, DH);
        gemm_final<<<dim3(B_ROWS / 128, DOUT / 128, g), 256, 0, stream>>>(
            h2, W3b + (size_t)t0 * DH * DOUT, out);
    }
}